// Round 5
// baseline (109.390 us; speedup 1.0000x reference)
//
#include <hip/hip_runtime.h>

// input : (64, 64, 12288) f32   -- (n, patch p=i*8+j, c*64*64 channel-major per patch)
// target: (64, 3, 512, 512) f32 -- ps = 64, n_patches = 8
// out = mean((input - patchify(target))^2)   (single f32 scalar)
//
// float4 geometry:
//   input  f4 idx = n*196608 + p*3072 + c*1024 + py*16 + px4
//   target f4 idx = n*196608 + c*65536 + (i*64+py)*128 + j*16 + px4
//
// R5: single fused kernel. Main loop identical to R4 (1024 blocks x 256 thr,
// launch_bounds(256,4) = exactly-resident, 4 patches/block, 96 static-offset
// loads/thread, nontemporal input so the 201 MB target stays L3-resident).
// The 1-block finalize kernel is replaced by a last-block-finalizes tail:
//   - block writes its partial via atomicExch (device-scope, coherent point,
//     immune to per-XCD L2 non-coherence)
//   - __threadfence() then atomicAdd(ctr) ; the block seeing old==NBLOCKS-1
//     re-reads partials via atomicAdd(p, 0.0f) (RMW read at coherent point)
//     and writes mean to d_out. No spin-wait -> no co-residency assumption.
// ctr (4 B at d_ws+4096) is zeroed each call via hipMemsetAsync (graph-safe).

#define NBLOCKS   1024
#define NTHREADS  256
#define INV_TOTAL (1.0 / 50331648.0)

using f32x4 = __attribute__((ext_vector_type(4))) float;

__global__ __launch_bounds__(NTHREADS, 4) void mse_fused_kernel(
    const f32x4* __restrict__ in,
    const f32x4* __restrict__ tgt,
    float* __restrict__ partial,
    unsigned int* __restrict__ ctr,
    float* __restrict__ out)
{
    const int b   = blockIdx.x;
    const int tid = threadIdx.x;

    const int n  = b >> 4;
    const int ii = (b & 15) >> 1;
    const int jj = (b & 1) << 2;

    const f32x4* ip = in + (size_t)b * 12288 + tid;
    const f32x4* tp = tgt + (size_t)n * 196608
                    + (size_t)((ii << 6) + (tid >> 4)) * 128
                    + (jj << 4) + (tid & 15);

    float a0 = 0.f, a1 = 0.f, a2 = 0.f, a3 = 0.f;

    #pragma unroll
    for (int pp = 0; pp < 4; ++pp) {
        f32x4 av[12], tv[12];
        #pragma unroll
        for (int k = 0; k < 12; ++k)
            av[k] = __builtin_nontemporal_load(ip + pp * 3072 + k * 256);
        #pragma unroll
        for (int k = 0; k < 12; ++k)
            tv[k] = tp[pp * 16 + (k >> 2) * 65536 + (k & 3) * 2048];
        #pragma unroll
        for (int k = 0; k < 12; ++k) {
            float dx = av[k].x - tv[k].x;
            float dy = av[k].y - tv[k].y;
            float dz = av[k].z - tv[k].z;
            float dw = av[k].w - tv[k].w;
            a0 = fmaf(dx, dx, a0);
            a1 = fmaf(dy, dy, a1);
            a2 = fmaf(dz, dz, a2);
            a3 = fmaf(dw, dw, a3);
        }
    }

    float acc = (a0 + a1) + (a2 + a3);

    #pragma unroll
    for (int off = 32; off > 0; off >>= 1)
        acc += __shfl_down(acc, off, 64);

    __shared__ float s[NTHREADS / 64];
    __shared__ int is_last;
    const int lane = threadIdx.x & 63;
    const int wave = threadIdx.x >> 6;
    if (lane == 0) s[wave] = acc;
    __syncthreads();

    if (tid == 0) {
        float bsum = (s[0] + s[1]) + (s[2] + s[3]);
        atomicExch(&partial[b], bsum);     // device-scope publish
        __threadfence();                    // order publish before counter
        unsigned int old = atomicAdd(ctr, 1u);
        is_last = (old == NBLOCKS - 1) ? 1 : 0;
    }
    __syncthreads();

    if (is_last) {
        // all 1023 other partials are published (their ctr increments happened
        // before ours); read them back through the coherent point.
        double dacc = 0.0;
        for (int i = tid; i < NBLOCKS; i += NTHREADS)
            dacc += (double)atomicAdd(&partial[i], 0.0f);

        #pragma unroll
        for (int off = 32; off > 0; off >>= 1)
            dacc += __shfl_down(dacc, off, 64);

        __shared__ double ds[NTHREADS / 64];
        if (lane == 0) ds[wave] = dacc;
        __syncthreads();
        if (tid == 0)
            out[0] = (float)(((ds[0] + ds[1]) + (ds[2] + ds[3])) * INV_TOTAL);
    }
}

extern "C" void kernel_launch(void* const* d_in, const int* in_sizes, int n_in,
                              void* d_out, int out_size, void* d_ws, size_t ws_size,
                              hipStream_t stream)
{
    const f32x4* in  = (const f32x4*)d_in[0];
    const f32x4* tgt = (const f32x4*)d_in[1];
    float* partial   = (float*)d_ws;                          // 1024 floats, overwritten every call
    unsigned int* ctr = (unsigned int*)((char*)d_ws + 4096);  // 4 B, zeroed below every call
    float* out       = (float*)d_out;

    hipMemsetAsync(ctr, 0, sizeof(unsigned int), stream);
    mse_fused_kernel<<<NBLOCKS, NTHREADS, 0, stream>>>(in, tgt, partial, ctr, out);
}

// Round 6
// 64.147 us; speedup vs baseline: 1.7053x; 1.7053x over previous
//
#include <hip/hip_runtime.h>

// input : (64, 64, 12288) f32   -- (n, patch p=i*8+j, c*64*64 channel-major per patch)
// target: (64, 3, 512, 512) f32 -- ps = 64, n_patches = 8
// out = mean((input - patchify(target))^2)   (single f32 scalar)
//
// float4 geometry:
//   input  f4 idx = n*196608 + p*3072 + c*1024 + py*16 + px4
//   target f4 idx = n*196608 + c*65536 + (i*64+py)*128 + j*16 + px4
//
// R6 = revert to R4 (best: 64.1 us). R5's fused last-block-finalizes tail
// (atomicExch + __threadfence + same-address atomicAdd from 1024
// simultaneously-finishing blocks) serialized at the device coherent point,
// +45 us. Two-kernel structure is the cheaper finalize.
//
// Structure: 1024 blocks x 256 thr @ launch_bounds(256,4) -> 4 blocks/CU,
// exactly resident. Block b owns 4 consecutive patches:
//   n = b>>4, ii = (b&15)>>1, jj = (b&1)<<2
// 96 loads/thread, every address = base + compile-time constant; input loads
// nontemporal so the 201 MB target stays L3-resident (FETCH_SIZE == input).

#define NBLOCKS   1024
#define NTHREADS  256
#define INV_TOTAL (1.0 / 50331648.0)

using f32x4 = __attribute__((ext_vector_type(4))) float;

__global__ __launch_bounds__(NTHREADS, 4) void mse_partial_kernel(
    const f32x4* __restrict__ in,
    const f32x4* __restrict__ tgt,
    float* __restrict__ partial)
{
    const int b   = blockIdx.x;
    const int tid = threadIdx.x;

    const int n  = b >> 4;
    const int ii = (b & 15) >> 1;
    const int jj = (b & 1) << 2;

    const f32x4* ip = in + (size_t)b * 12288 + tid;
    const f32x4* tp = tgt + (size_t)n * 196608
                    + (size_t)((ii << 6) + (tid >> 4)) * 128
                    + (jj << 4) + (tid & 15);

    float a0 = 0.f, a1 = 0.f, a2 = 0.f, a3 = 0.f;

    #pragma unroll
    for (int pp = 0; pp < 4; ++pp) {
        f32x4 av[12], tv[12];
        #pragma unroll
        for (int k = 0; k < 12; ++k)
            av[k] = __builtin_nontemporal_load(ip + pp * 3072 + k * 256);
        #pragma unroll
        for (int k = 0; k < 12; ++k)
            tv[k] = tp[pp * 16 + (k >> 2) * 65536 + (k & 3) * 2048];
        #pragma unroll
        for (int k = 0; k < 12; ++k) {
            float dx = av[k].x - tv[k].x;
            float dy = av[k].y - tv[k].y;
            float dz = av[k].z - tv[k].z;
            float dw = av[k].w - tv[k].w;
            a0 = fmaf(dx, dx, a0);
            a1 = fmaf(dy, dy, a1);
            a2 = fmaf(dz, dz, a2);
            a3 = fmaf(dw, dw, a3);
        }
    }

    float acc = (a0 + a1) + (a2 + a3);

    #pragma unroll
    for (int off = 32; off > 0; off >>= 1)
        acc += __shfl_down(acc, off, 64);

    __shared__ float s[NTHREADS / 64];
    const int lane = threadIdx.x & 63;
    const int wave = threadIdx.x >> 6;
    if (lane == 0) s[wave] = acc;
    __syncthreads();
    if (threadIdx.x == 0)
        partial[blockIdx.x] = s[0] + s[1] + s[2] + s[3];
}

__global__ __launch_bounds__(NTHREADS) void mse_final_kernel(
    const float* __restrict__ partial,
    float* __restrict__ out)
{
    double acc = 0.0;
    for (int i = threadIdx.x; i < NBLOCKS; i += NTHREADS)
        acc += (double)partial[i];

    #pragma unroll
    for (int off = 32; off > 0; off >>= 1)
        acc += __shfl_down(acc, off, 64);

    __shared__ double s[NTHREADS / 64];
    const int lane = threadIdx.x & 63;
    const int wave = threadIdx.x >> 6;
    if (lane == 0) s[wave] = acc;
    __syncthreads();
    if (threadIdx.x == 0)
        out[0] = (float)((s[0] + s[1] + s[2] + s[3]) * INV_TOTAL);
}

extern "C" void kernel_launch(void* const* d_in, const int* in_sizes, int n_in,
                              void* d_out, int out_size, void* d_ws, size_t ws_size,
                              hipStream_t stream)
{
    const f32x4* in  = (const f32x4*)d_in[0];
    const f32x4* tgt = (const f32x4*)d_in[1];
    float* partial   = (float*)d_ws;    // NBLOCKS floats, fully rewritten every call
    float* out       = (float*)d_out;

    mse_partial_kernel<<<NBLOCKS, NTHREADS, 0, stream>>>(in, tgt, partial);
    mse_final_kernel<<<1, NTHREADS, 0, stream>>>(partial, out);
}